// Round 5
// baseline (643.596 us; speedup 1.0000x reference)
//
#include <hip/hip_runtime.h>

// Fused 3-layer LSTM + dense head, layer-pipelined wave specialization.
// B=2048, T=256, F=64, H=[64,32,16], OUT=1. fp32 in/out.
//
// bf16 3-term split MFMA (ah*wh + al*wh + ah*wl) for ~2^-16 precision.
// Block = 512 threads = 8 waves, grid = 256 (1 block/CU, BT=8 batches).
//   waves 0-3 : layer0 at step t    waves 4-5 : layer1 at t-1
//   wave  6   : layer2 at t-2       wave  7   : x-stager (t+1, 2-deep pipeline)
//
// Round-5 fix vs round 4:
//  * amdgpu_waves_per_eu(2,2) + amdgpu_flat_work_group_size(512,512) replaces
//    __launch_bounds__(512,2). Rounds 3/4 allocated only 104 VGPRs (compiler
//    targeted 4 waves/EU occupancy since only a MIN was declared) and
//    rematerialized the ~128-VGPR weight-fragment set from global+f2bf every
//    step (~3100 VALU cyc/SIMD-step = the measured VALUBusy gap). max=2
//    waves/EU grants the full 256-VGPR budget so the PINned fragments can
//    stay register-resident.
//  * PIN(): asm anchors marking weight frags as opaque register values.
//  * BAR(): raw `s_waitcnt lgkmcnt(0); s_barrier` (no vmcnt(0) drain of the
//    stager's in-flight HBM prefetch; all cross-wave deps are LDS-only).

typedef __attribute__((ext_vector_type(8))) short s8v;   // 8 x bf16
typedef __attribute__((ext_vector_type(4))) float f4v;   // 4 x f32
typedef unsigned short ushort_t;

#define T_STEPS 256
#define BT 8

// SMEM layout (units: shorts). chunk = [kgrp 0..3][row 0..15][j 0..7] = 512 shorts.
#define XH  0       // [par][2 chunks]
#define XL  2048
#define H0H 4096    // [par][2 chunks]
#define H0L 6144
#define H1H 8192    // [par][1 chunk]
#define H1L 9216
#define H2H 10240   // [par][1 chunk] (k 16..31 = zero pad)
#define H2L 11264
#define SM_SHORTS 12288

#define PIN(v) asm volatile("" : "+v"(v))
#define BAR()  asm volatile("s_waitcnt lgkmcnt(0)\n\ts_barrier" ::: "memory")

__device__ __forceinline__ unsigned short f2bf(float f) {
    unsigned u = __float_as_uint(f);
    u += 0x7fff + ((u >> 16) & 1);          // round-to-nearest-even
    return (unsigned short)(u >> 16);
}
__device__ __forceinline__ float bf2f(unsigned short s) {
    return __uint_as_float(((unsigned)s) << 16);
}
__device__ __forceinline__ float sigmoid_f(float x) { return 1.0f / (1.0f + __expf(-x)); }
__device__ __forceinline__ float tanh_f(float x)    { return 1.0f - 2.0f / (__expf(2.0f * x) + 1.0f); }

// combined [W;U] weight element, zero-padded past KH rows
__device__ __forceinline__ float wval(const float* W, const float* U,
                                      int inDim, int KH, int fourH, int k, int n) {
    if (k < inDim) return W[k * fourH + n];
    if (k < KH)    return U[(k - inDim) * fourH + n];
    return 0.0f;
}
__device__ __forceinline__ void load_bfrag(const float* W, const float* U,
                                           int inDim, int KH, int fourH,
                                           int k0, int n, s8v& hi, s8v& lo) {
#pragma unroll
    for (int j = 0; j < 8; ++j) {
        float w = wval(W, U, inDim, KH, fourH, k0 + j, n);
        unsigned short h = f2bf(w);
        unsigned short l = f2bf(w - bf2f(h));
        hi[j] = (short)h;
        lo[j] = (short)l;
    }
}

__device__ __forceinline__ void gates4(const f4v* acc, float* c, float* hn) {
#pragma unroll
    for (int r = 0; r < 4; ++r) {
        float ig = sigmoid_f(acc[0][r]);
        float fg = sigmoid_f(acc[1][r]);
        float gg = tanh_f(acc[2][r]);
        float og = sigmoid_f(acc[3][r]);
        c[r] = fg * c[r] + ig * gg;
        hn[r] = og * tanh_f(c[r]);
    }
}

// write 4 batch-rows of one h-unit (k-position k in a chunk) as bf16 hi/lo
__device__ __forceinline__ void write_h(ushort_t* dh, ushort_t* dl, int k, int fr,
                                        const float* hn) {
    if (fr < 2) {
        int ib = (k >> 3) * 128 + (k & 7);
#pragma unroll
        for (int r = 0; r < 4; ++r) {
            int b = fr * 4 + r;
            unsigned short hh_ = f2bf(hn[r]);
            dh[ib + b * 8] = hh_;
            dl[ib + b * 8] = f2bf(hn[r] - bf2f(hh_));
        }
    }
}

__global__ __attribute__((amdgpu_flat_work_group_size(512, 512),
                          amdgpu_waves_per_eu(2, 2)))
void lstm_pipe(const float* __restrict__ x,
               const float* __restrict__ W0, const float* __restrict__ U0, const float* __restrict__ b0,
               const float* __restrict__ W1, const float* __restrict__ U1, const float* __restrict__ b1,
               const float* __restrict__ W2, const float* __restrict__ U2, const float* __restrict__ b2,
               const float* __restrict__ Wd, const float* __restrict__ bd,
               float* __restrict__ out)
{
    const int tid  = threadIdx.x;
    const int lane = tid & 63;
    const int wv   = tid >> 6;          // 0..7
    const int fr   = lane >> 4;         // k-group / C row-group
    const int fc   = lane & 15;         // frag column
    const int bbase = blockIdx.x * BT;

    __shared__ __align__(16) ushort_t SMEM[SM_SHORTS];
    __shared__ __align__(16) float h2last[BT][16];

    // zero all staging (rows 8..15 of every chunk must stay zero; h init = 0)
    {
        unsigned* p32 = (unsigned*)SMEM;
        for (int i = tid; i < SM_SHORTS / 2; i += 512) p32[i] = 0u;
    }
    __syncthreads();                                    // barrier #1

    if (wv < 4) {
        // =================== layer0 role (waves 0..3) ===================
        s8v Bh[4][4], Bl[4][4];                         // [gate][kc]
        float bias[4];
#pragma unroll
        for (int g = 0; g < 4; ++g) {
            int n = g * 64 + wv * 16 + fc;
            bias[g] = b0[n];
#pragma unroll
            for (int kc = 0; kc < 4; ++kc)
                load_bfrag(W0, U0, 64, 128, 256, kc * 32 + fr * 8, n, Bh[g][kc], Bl[g][kc]);
        }
#pragma unroll
        for (int g = 0; g < 4; ++g) {
            PIN(bias[g]);
#pragma unroll
            for (int kc = 0; kc < 4; ++kc) { PIN(Bh[g][kc]); PIN(Bl[g][kc]); }
        }
        float c0[4] = {0.f, 0.f, 0.f, 0.f};
        __syncthreads();                                // barrier #2
        for (int s = 0; s < T_STEPS + 2; ++s) {
            if (s < T_STEPS) {
                int p = s & 1;
                s8v ah[4], al[4];
                ah[0] = *(const s8v*)&SMEM[XH  + (p * 2 + 0) * 512 + lane * 8];
                al[0] = *(const s8v*)&SMEM[XL  + (p * 2 + 0) * 512 + lane * 8];
                ah[1] = *(const s8v*)&SMEM[XH  + (p * 2 + 1) * 512 + lane * 8];
                al[1] = *(const s8v*)&SMEM[XL  + (p * 2 + 1) * 512 + lane * 8];
                ah[2] = *(const s8v*)&SMEM[H0H + (p * 2 + 0) * 512 + lane * 8];
                al[2] = *(const s8v*)&SMEM[H0L + (p * 2 + 0) * 512 + lane * 8];
                ah[3] = *(const s8v*)&SMEM[H0H + (p * 2 + 1) * 512 + lane * 8];
                al[3] = *(const s8v*)&SMEM[H0L + (p * 2 + 1) * 512 + lane * 8];
                f4v acc[4];
#pragma unroll
                for (int g = 0; g < 4; ++g) acc[g] = (f4v){bias[g], bias[g], bias[g], bias[g]};
#pragma unroll
                for (int kc = 0; kc < 4; ++kc)
#pragma unroll
                    for (int g = 0; g < 4; ++g) {
                        acc[g] = __builtin_amdgcn_mfma_f32_16x16x32_bf16(ah[kc], Bh[g][kc], acc[g], 0, 0, 0);
                        acc[g] = __builtin_amdgcn_mfma_f32_16x16x32_bf16(al[kc], Bh[g][kc], acc[g], 0, 0, 0);
                        acc[g] = __builtin_amdgcn_mfma_f32_16x16x32_bf16(ah[kc], Bl[g][kc], acc[g], 0, 0, 0);
                    }
                float hn[4];
                gates4(acc, c0, hn);
                int hq = wv >> 1;                       // h0 chunk
                int k  = (wv & 1) * 16 + fc;            // k within chunk
                write_h(&SMEM[H0H + ((1 - p) * 2 + hq) * 512],
                        &SMEM[H0L + ((1 - p) * 2 + hq) * 512], k, fr, hn);
            }
            BAR();
        }
    } else if (wv < 6) {
        // =================== layer1 role (waves 4,5) ===================
        s8v Bh[4][3], Bl[4][3];
        float bias[4];
#pragma unroll
        for (int g = 0; g < 4; ++g) {
            int n = g * 32 + (wv & 1) * 16 + fc;
            bias[g] = b1[n];
#pragma unroll
            for (int kc = 0; kc < 3; ++kc)
                load_bfrag(W1, U1, 64, 96, 128, kc * 32 + fr * 8, n, Bh[g][kc], Bl[g][kc]);
        }
#pragma unroll
        for (int g = 0; g < 4; ++g) {
            PIN(bias[g]);
#pragma unroll
            for (int kc = 0; kc < 3; ++kc) { PIN(Bh[g][kc]); PIN(Bl[g][kc]); }
        }
        float c1[4] = {0.f, 0.f, 0.f, 0.f};
        __syncthreads();                                // barrier #2
        for (int s = 0; s < T_STEPS + 2; ++s) {
            if (s >= 1 && s <= T_STEPS) {
                int p = s & 1;
                s8v ah[3], al[3];
                ah[0] = *(const s8v*)&SMEM[H0H + (p * 2 + 0) * 512 + lane * 8];
                al[0] = *(const s8v*)&SMEM[H0L + (p * 2 + 0) * 512 + lane * 8];
                ah[1] = *(const s8v*)&SMEM[H0H + (p * 2 + 1) * 512 + lane * 8];
                al[1] = *(const s8v*)&SMEM[H0L + (p * 2 + 1) * 512 + lane * 8];
                ah[2] = *(const s8v*)&SMEM[H1H + p * 512 + lane * 8];
                al[2] = *(const s8v*)&SMEM[H1L + p * 512 + lane * 8];
                f4v acc[4];
#pragma unroll
                for (int g = 0; g < 4; ++g) acc[g] = (f4v){bias[g], bias[g], bias[g], bias[g]};
#pragma unroll
                for (int kc = 0; kc < 3; ++kc)
#pragma unroll
                    for (int g = 0; g < 4; ++g) {
                        acc[g] = __builtin_amdgcn_mfma_f32_16x16x32_bf16(ah[kc], Bh[g][kc], acc[g], 0, 0, 0);
                        acc[g] = __builtin_amdgcn_mfma_f32_16x16x32_bf16(al[kc], Bh[g][kc], acc[g], 0, 0, 0);
                        acc[g] = __builtin_amdgcn_mfma_f32_16x16x32_bf16(ah[kc], Bl[g][kc], acc[g], 0, 0, 0);
                    }
                float hn[4];
                gates4(acc, c1, hn);
                int k = (wv & 1) * 16 + fc;
                write_h(&SMEM[H1H + (1 - p) * 512],
                        &SMEM[H1L + (1 - p) * 512], k, fr, hn);
            }
            BAR();
        }
    } else if (wv == 6) {
        // =================== layer2 role (wave 6) ===================
        s8v Bh[4][2], Bl[4][2];
        float bias[4];
#pragma unroll
        for (int g = 0; g < 4; ++g) {
            int n = g * 16 + fc;
            bias[g] = b2[n];
#pragma unroll
            for (int kc = 0; kc < 2; ++kc)
                load_bfrag(W2, U2, 32, 48, 64, kc * 32 + fr * 8, n, Bh[g][kc], Bl[g][kc]);
        }
#pragma unroll
        for (int g = 0; g < 4; ++g) {
            PIN(bias[g]);
#pragma unroll
            for (int kc = 0; kc < 2; ++kc) { PIN(Bh[g][kc]); PIN(Bl[g][kc]); }
        }
        float c2[4] = {0.f, 0.f, 0.f, 0.f};
        __syncthreads();                                // barrier #2
        for (int s = 0; s < T_STEPS + 2; ++s) {
            if (s >= 2) {
                int p = s & 1;
                s8v ah[2], al[2];
                ah[0] = *(const s8v*)&SMEM[H1H + p * 512 + lane * 8];
                al[0] = *(const s8v*)&SMEM[H1L + p * 512 + lane * 8];
                ah[1] = *(const s8v*)&SMEM[H2H + p * 512 + lane * 8];
                al[1] = *(const s8v*)&SMEM[H2L + p * 512 + lane * 8];
                f4v acc[4];
#pragma unroll
                for (int g = 0; g < 4; ++g) acc[g] = (f4v){bias[g], bias[g], bias[g], bias[g]};
#pragma unroll
                for (int kc = 0; kc < 2; ++kc)
#pragma unroll
                    for (int g = 0; g < 4; ++g) {
                        acc[g] = __builtin_amdgcn_mfma_f32_16x16x32_bf16(ah[kc], Bh[g][kc], acc[g], 0, 0, 0);
                        acc[g] = __builtin_amdgcn_mfma_f32_16x16x32_bf16(al[kc], Bh[g][kc], acc[g], 0, 0, 0);
                        acc[g] = __builtin_amdgcn_mfma_f32_16x16x32_bf16(ah[kc], Bl[g][kc], acc[g], 0, 0, 0);
                    }
                float hn[4];
                gates4(acc, c2, hn);
                write_h(&SMEM[H2H + (1 - p) * 512],
                        &SMEM[H2L + (1 - p) * 512], fc, fr, hn);
                if (s == T_STEPS + 1 && fr < 2) {       // t2 = 255: final h2
#pragma unroll
                    for (int r = 0; r < 4; ++r) h2last[fr * 4 + r][fc] = hn[r];
                }
            }
            BAR();
        }
    } else {
        // =================== x-stager role (wave 7), 2-deep pipeline ===================
        const int xb = lane >> 3;                       // batch row 0..7
        const int fo = (lane & 7) * 8;                  // feature octet base
        const float* xp = x + ((size_t)(bbase + xb) * T_STEPS) * 64 + fo;
        const int c_  = fo >> 5;                        // x chunk 0/1
        const int kg  = (fo & 31) >> 3;                 // k-group in chunk
        const int o_  = (kg * 16 + xb) * 8;             // element offset

        auto write_x = [&](float4 v0, float4 v1, int tt) {
            float vv[8] = {v0.x, v0.y, v0.z, v0.w, v1.x, v1.y, v1.z, v1.w};
            s8v hi8, lo8;
#pragma unroll
            for (int j = 0; j < 8; ++j) {
                unsigned short h = f2bf(vv[j]);
                hi8[j] = (short)h;
                lo8[j] = (short)f2bf(vv[j] - bf2f(h));
            }
            int buf = tt & 1;
            *(s8v*)&SMEM[XH + (buf * 2 + c_) * 512 + o_] = hi8;
            *(s8v*)&SMEM[XL + (buf * 2 + c_) * 512 + o_] = lo8;
        };

        // prologue: write x(0), prefetch x(1) into regs
        float4 pa = *(const float4*)(xp);
        float4 pb = *(const float4*)(xp + 4);
        write_x(pa, pb, 0);
        pa = *(const float4*)(xp + 64);
        pb = *(const float4*)(xp + 64 + 4);
        __syncthreads();                                // barrier #2
        for (int s = 0; s < T_STEPS + 2; ++s) {
            float4 na, nb;
            const bool ld = (s + 2 < T_STEPS);
            if (ld) {                                   // issue x(s+2) early
                na = *(const float4*)(xp + (size_t)(s + 2) * 64);
                nb = *(const float4*)(xp + (size_t)(s + 2) * 64 + 4);
            }
            if (s + 1 < T_STEPS) write_x(pa, pb, s + 1);   // waits on load from s-1
            if (ld) { pa = na; pb = nb; }
            BAR();
        }
    }

    __syncthreads();
    // =================== dense head ===================
    if (tid < BT) {
        float acc = bd[0];
#pragma unroll
        for (int j = 0; j < 16; ++j) acc += h2last[tid][j] * Wd[j];
        out[bbase + tid] = acc;
    }
}

extern "C" void kernel_launch(void* const* d_in, const int* in_sizes, int n_in,
                              void* d_out, int out_size, void* d_ws, size_t ws_size,
                              hipStream_t stream) {
    (void)in_sizes; (void)n_in; (void)d_ws; (void)ws_size; (void)out_size;
    const float* x  = (const float*)d_in[0];
    const float* W0 = (const float*)d_in[1];
    const float* U0 = (const float*)d_in[2];
    const float* b0 = (const float*)d_in[3];
    const float* W1 = (const float*)d_in[4];
    const float* U1 = (const float*)d_in[5];
    const float* b1 = (const float*)d_in[6];
    const float* W2 = (const float*)d_in[7];
    const float* U2 = (const float*)d_in[8];
    const float* b2 = (const float*)d_in[9];
    const float* Wd = (const float*)d_in[10];
    const float* bd = (const float*)d_in[11];
    float* out = (float*)d_out;

    dim3 grid(2048 / BT);   // 256 blocks, 1 per CU
    dim3 block(512);        // 8 waves, 2 per SIMD
    hipLaunchKernelGGL(lstm_pipe, grid, block, 0, stream,
                       x, W0, U0, b0, W1, U1, b1, W2, U2, b2, Wd, bd, out);
}

// Round 6
// 456.677 us; speedup vs baseline: 1.4093x; 1.4093x over previous
//
#include <hip/hip_runtime.h>

// Fused 3-layer LSTM + dense head, layer-pipelined wave specialization.
// B=2048, T=256, F=64, H=[64,32,16], OUT=1. fp32 in/out.
//
// bf16 3-term split MFMA (ah*wh + al*wh + ah*wl) for ~2^-16 precision.
// Block = 512 threads = 8 waves, grid = 256 (1 block/CU, BT=8 batches).
//   waves 0-3 : layer0 at step t    waves 4-5 : layer1 at t-1
//   wave  6   : layer2 at t-2       wave  7   : x-stager (t+1, 2-deep pipeline)
//
// Round-6 changes (VALU issue was the bottleneck: 3100 cyc/SIMD-step at 58%):
//  * sigmoid/tanh via __builtin_amdgcn_rcpf: without fast-math, `1.0f/x`
//    compiled to the full IEEE div sequence (~13 insts); 5 divs per h-unit
//    row x 4 rows x 2 gate-waves/SIMD was ~1/3 of all VALU issue.
//  * truncation-based hi/lo bf16 splits for staged activations (4 insts/value
//    vs ~10 for RTNE; residual is exact so error stays ~2^-16). Weights keep
//    RTNE (one-time cost).
//  * per-role LDS base pointer + parity add once per step; chunk/row offsets
//    fold into ds_read/ds_write 16-bit immediate offsets.

typedef __attribute__((ext_vector_type(8))) short s8v;   // 8 x bf16
typedef __attribute__((ext_vector_type(4))) float f4v;   // 4 x f32
typedef unsigned short ushort_t;

#define T_STEPS 256
#define BT 8

// SMEM layout (units: shorts). chunk = [kgrp 0..3][row 0..15][j 0..7] = 512 shorts.
#define XH  0       // [par][2 chunks], parity stride 1024
#define XL  2048
#define H0H 4096    // [par][2 chunks], parity stride 1024
#define H0L 6144
#define H1H 8192    // [par][1 chunk],  parity stride 512
#define H1L 9216
#define H2H 10240   // [par][1 chunk],  parity stride 512 (k 16..31 = zero pad)
#define H2L 11264
#define SM_SHORTS 12288

#define PIN(v) asm volatile("" : "+v"(v))
#define BAR()  asm volatile("s_waitcnt lgkmcnt(0)\n\ts_barrier" ::: "memory")

__device__ __forceinline__ unsigned short f2bf(float f) {      // RTNE (weights, one-time)
    unsigned u = __float_as_uint(f);
    u += 0x7fff + ((u >> 16) & 1);
    return (unsigned short)(u >> 16);
}
__device__ __forceinline__ float bf2f(unsigned short s) {
    return __uint_as_float(((unsigned)s) << 16);
}
// cheap truncation split: hi = top 16 bits, lo = trunc(v - hi). Error <= 2^-16*|v|.
__device__ __forceinline__ void tsplit(float v, unsigned short& hi, unsigned short& lo) {
    unsigned u = __float_as_uint(v);
    hi = (unsigned short)(u >> 16);
    float r = v - __uint_as_float(u & 0xffff0000u);   // exact
    lo = (unsigned short)(__float_as_uint(r) >> 16);
}
__device__ __forceinline__ float sigmoid_f(float x) {
    return __builtin_amdgcn_rcpf(1.0f + __expf(-x));
}
__device__ __forceinline__ float tanh_f(float x) {
    return 1.0f - 2.0f * __builtin_amdgcn_rcpf(__expf(2.0f * x) + 1.0f);
}

// combined [W;U] weight element, zero-padded past KH rows
__device__ __forceinline__ float wval(const float* W, const float* U,
                                      int inDim, int KH, int fourH, int k, int n) {
    if (k < inDim) return W[k * fourH + n];
    if (k < KH)    return U[(k - inDim) * fourH + n];
    return 0.0f;
}
__device__ __forceinline__ void load_bfrag(const float* W, const float* U,
                                           int inDim, int KH, int fourH,
                                           int k0, int n, s8v& hi, s8v& lo) {
#pragma unroll
    for (int j = 0; j < 8; ++j) {
        float w = wval(W, U, inDim, KH, fourH, k0 + j, n);
        unsigned short h = f2bf(w);
        unsigned short l = f2bf(w - bf2f(h));
        hi[j] = (short)h;
        lo[j] = (short)l;
    }
}

__device__ __forceinline__ void gates4(const f4v* acc, float* c, float* hn) {
#pragma unroll
    for (int r = 0; r < 4; ++r) {
        float ig = sigmoid_f(acc[0][r]);
        float fg = sigmoid_f(acc[1][r]);
        float gg = tanh_f(acc[2][r]);
        float og = sigmoid_f(acc[3][r]);
        c[r] = fmaf(fg, c[r], ig * gg);
        hn[r] = og * tanh_f(c[r]);
    }
}

__global__ __attribute__((amdgpu_flat_work_group_size(512, 512),
                          amdgpu_waves_per_eu(2, 2)))
void lstm_pipe(const float* __restrict__ x,
               const float* __restrict__ W0, const float* __restrict__ U0, const float* __restrict__ b0,
               const float* __restrict__ W1, const float* __restrict__ U1, const float* __restrict__ b1,
               const float* __restrict__ W2, const float* __restrict__ U2, const float* __restrict__ b2,
               const float* __restrict__ Wd, const float* __restrict__ bd,
               float* __restrict__ out)
{
    const int tid  = threadIdx.x;
    const int lane = tid & 63;
    const int wv   = tid >> 6;          // 0..7
    const int fr   = lane >> 4;         // k-group / C row-group
    const int fc   = lane & 15;         // frag column
    const int bbase = blockIdx.x * BT;

    __shared__ __align__(16) ushort_t SMEM[SM_SHORTS];
    __shared__ __align__(16) float h2last[BT][16];

    // zero all staging (rows 8..15 of every chunk must stay zero; h init = 0)
    {
        unsigned* p32 = (unsigned*)SMEM;
        for (int i = tid; i < SM_SHORTS / 2; i += 512) p32[i] = 0u;
    }
    __syncthreads();                                    // barrier #1

    const ushort_t* rb = SMEM + lane * 8;               // frag read base (all roles)

    if (wv < 4) {
        // =================== layer0 role (waves 0..3) ===================
        s8v Bh[4][4], Bl[4][4];                         // [gate][kc]
        float bias[4];
#pragma unroll
        for (int g = 0; g < 4; ++g) {
            int n = g * 64 + wv * 16 + fc;
            bias[g] = b0[n];
#pragma unroll
            for (int kc = 0; kc < 4; ++kc)
                load_bfrag(W0, U0, 64, 128, 256, kc * 32 + fr * 8, n, Bh[g][kc], Bl[g][kc]);
        }
#pragma unroll
        for (int g = 0; g < 4; ++g) {
            PIN(bias[g]);
#pragma unroll
            for (int kc = 0; kc < 4; ++kc) { PIN(Bh[g][kc]); PIN(Bl[g][kc]); }
        }
        float c0[4] = {0.f, 0.f, 0.f, 0.f};
        const int hq  = wv >> 1;                        // h0 chunk this wave writes
        const int k   = (wv & 1) * 16 + fc;             // k within chunk
        const int ibw = (k >> 3) * 128 + (k & 7);       // lane-dep write offset
        __syncthreads();                                // barrier #2
        for (int s = 0; s < T_STEPS + 2; ++s) {
            if (s < T_STEPS) {
                const ushort_t* r = rb + ((s & 1) << 10);   // parity*1024 shorts
                s8v ah[4], al[4];
                ah[0] = *(const s8v*)&r[XH  +   0];
                al[0] = *(const s8v*)&r[XL  +   0];
                ah[1] = *(const s8v*)&r[XH  + 512];
                al[1] = *(const s8v*)&r[XL  + 512];
                ah[2] = *(const s8v*)&r[H0H +   0];
                al[2] = *(const s8v*)&r[H0L +   0];
                ah[3] = *(const s8v*)&r[H0H + 512];
                al[3] = *(const s8v*)&r[H0L + 512];
                f4v acc[4];
#pragma unroll
                for (int g = 0; g < 4; ++g) acc[g] = (f4v){bias[g], bias[g], bias[g], bias[g]};
#pragma unroll
                for (int kc = 0; kc < 4; ++kc)
#pragma unroll
                    for (int g = 0; g < 4; ++g) {
                        acc[g] = __builtin_amdgcn_mfma_f32_16x16x32_bf16(ah[kc], Bh[g][kc], acc[g], 0, 0, 0);
                        acc[g] = __builtin_amdgcn_mfma_f32_16x16x32_bf16(al[kc], Bh[g][kc], acc[g], 0, 0, 0);
                        acc[g] = __builtin_amdgcn_mfma_f32_16x16x32_bf16(ah[kc], Bl[g][kc], acc[g], 0, 0, 0);
                    }
                float hn[4];
                gates4(acc, c0, hn);
                if (fr < 2) {
                    ushort_t* w = SMEM + (((s & 1) ^ 1) << 10) + hq * 512 + ibw;
#pragma unroll
                    for (int r_ = 0; r_ < 4; ++r_) {
                        unsigned short hh_, ll_;
                        tsplit(hn[r_], hh_, ll_);
                        w[H0H + (fr * 4 + r_) * 8] = hh_;
                        w[H0L + (fr * 4 + r_) * 8] = ll_;
                    }
                }
            }
            BAR();
        }
    } else if (wv < 6) {
        // =================== layer1 role (waves 4,5) ===================
        s8v Bh[4][3], Bl[4][3];
        float bias[4];
#pragma unroll
        for (int g = 0; g < 4; ++g) {
            int n = g * 32 + (wv & 1) * 16 + fc;
            bias[g] = b1[n];
#pragma unroll
            for (int kc = 0; kc < 3; ++kc)
                load_bfrag(W1, U1, 64, 96, 128, kc * 32 + fr * 8, n, Bh[g][kc], Bl[g][kc]);
        }
#pragma unroll
        for (int g = 0; g < 4; ++g) {
            PIN(bias[g]);
#pragma unroll
            for (int kc = 0; kc < 3; ++kc) { PIN(Bh[g][kc]); PIN(Bl[g][kc]); }
        }
        float c1[4] = {0.f, 0.f, 0.f, 0.f};
        const int k   = (wv & 1) * 16 + fc;
        const int ibw = (k >> 3) * 128 + (k & 7);
        __syncthreads();                                // barrier #2
        for (int s = 0; s < T_STEPS + 2; ++s) {
            if (s >= 1 && s <= T_STEPS) {
                const int p = s & 1;
                const ushort_t* r  = rb + (p << 10);    // H0 parity stride 1024
                const ushort_t* r1 = rb + (p << 9);     // H1 parity stride 512
                s8v ah[3], al[3];
                ah[0] = *(const s8v*)&r[H0H +   0];
                al[0] = *(const s8v*)&r[H0L +   0];
                ah[1] = *(const s8v*)&r[H0H + 512];
                al[1] = *(const s8v*)&r[H0L + 512];
                ah[2] = *(const s8v*)&r1[H1H];
                al[2] = *(const s8v*)&r1[H1L];
                f4v acc[4];
#pragma unroll
                for (int g = 0; g < 4; ++g) acc[g] = (f4v){bias[g], bias[g], bias[g], bias[g]};
#pragma unroll
                for (int kc = 0; kc < 3; ++kc)
#pragma unroll
                    for (int g = 0; g < 4; ++g) {
                        acc[g] = __builtin_amdgcn_mfma_f32_16x16x32_bf16(ah[kc], Bh[g][kc], acc[g], 0, 0, 0);
                        acc[g] = __builtin_amdgcn_mfma_f32_16x16x32_bf16(al[kc], Bh[g][kc], acc[g], 0, 0, 0);
                        acc[g] = __builtin_amdgcn_mfma_f32_16x16x32_bf16(ah[kc], Bl[g][kc], acc[g], 0, 0, 0);
                    }
                float hn[4];
                gates4(acc, c1, hn);
                if (fr < 2) {
                    ushort_t* w = SMEM + ((p ^ 1) << 9) + ibw;
#pragma unroll
                    for (int r_ = 0; r_ < 4; ++r_) {
                        unsigned short hh_, ll_;
                        tsplit(hn[r_], hh_, ll_);
                        w[H1H + (fr * 4 + r_) * 8] = hh_;
                        w[H1L + (fr * 4 + r_) * 8] = ll_;
                    }
                }
            }
            BAR();
        }
    } else if (wv == 6) {
        // =================== layer2 role (wave 6) ===================
        s8v Bh[4][2], Bl[4][2];
        float bias[4];
#pragma unroll
        for (int g = 0; g < 4; ++g) {
            int n = g * 16 + fc;
            bias[g] = b2[n];
#pragma unroll
            for (int kc = 0; kc < 2; ++kc)
                load_bfrag(W2, U2, 32, 48, 64, kc * 32 + fr * 8, n, Bh[g][kc], Bl[g][kc]);
        }
#pragma unroll
        for (int g = 0; g < 4; ++g) {
            PIN(bias[g]);
#pragma unroll
            for (int kc = 0; kc < 2; ++kc) { PIN(Bh[g][kc]); PIN(Bl[g][kc]); }
        }
        float c2[4] = {0.f, 0.f, 0.f, 0.f};
        const int ibw = (fc >> 3) * 128 + (fc & 7);     // k = fc (0..15)
        __syncthreads();                                // barrier #2
        for (int s = 0; s < T_STEPS + 2; ++s) {
            if (s >= 2) {
                const int p = s & 1;
                const ushort_t* r1 = rb + (p << 9);     // H1,H2 parity stride 512
                s8v ah[2], al[2];
                ah[0] = *(const s8v*)&r1[H1H];
                al[0] = *(const s8v*)&r1[H1L];
                ah[1] = *(const s8v*)&r1[H2H];
                al[1] = *(const s8v*)&r1[H2L];
                f4v acc[4];
#pragma unroll
                for (int g = 0; g < 4; ++g) acc[g] = (f4v){bias[g], bias[g], bias[g], bias[g]};
#pragma unroll
                for (int kc = 0; kc < 2; ++kc)
#pragma unroll
                    for (int g = 0; g < 4; ++g) {
                        acc[g] = __builtin_amdgcn_mfma_f32_16x16x32_bf16(ah[kc], Bh[g][kc], acc[g], 0, 0, 0);
                        acc[g] = __builtin_amdgcn_mfma_f32_16x16x32_bf16(al[kc], Bh[g][kc], acc[g], 0, 0, 0);
                        acc[g] = __builtin_amdgcn_mfma_f32_16x16x32_bf16(ah[kc], Bl[g][kc], acc[g], 0, 0, 0);
                    }
                float hn[4];
                gates4(acc, c2, hn);
                if (fr < 2) {
                    ushort_t* w = SMEM + ((p ^ 1) << 9) + ibw;
#pragma unroll
                    for (int r_ = 0; r_ < 4; ++r_) {
                        unsigned short hh_, ll_;
                        tsplit(hn[r_], hh_, ll_);
                        w[H2H + (fr * 4 + r_) * 8] = hh_;
                        w[H2L + (fr * 4 + r_) * 8] = ll_;
                    }
                    if (s == T_STEPS + 1) {             // t2 = 255: final h2
#pragma unroll
                        for (int r_ = 0; r_ < 4; ++r_) h2last[fr * 4 + r_][fc] = hn[r_];
                    }
                }
            }
            BAR();
        }
    } else {
        // =================== x-stager role (wave 7), 2-deep pipeline ===================
        const int xb = lane >> 3;                       // batch row 0..7
        const int fo = (lane & 7) * 8;                  // feature octet base
        const float* xp = x + ((size_t)(bbase + xb) * T_STEPS) * 64 + fo;
        const int o2 = (fo >> 5) * 512 + (((fo & 31) >> 3) * 16 + xb) * 8;

        auto write_x = [&](float4 v0, float4 v1, int tt) {
            float vv[8] = {v0.x, v0.y, v0.z, v0.w, v1.x, v1.y, v1.z, v1.w};
            s8v hi8, lo8;
#pragma unroll
            for (int j = 0; j < 8; ++j) {
                unsigned short h_, l_;
                tsplit(vv[j], h_, l_);
                hi8[j] = (short)h_;
                lo8[j] = (short)l_;
            }
            ushort_t* wbp = SMEM + ((tt & 1) << 10) + o2;
            *(s8v*)&wbp[XH] = hi8;
            *(s8v*)&wbp[XL] = lo8;
        };

        // prologue: write x(0), prefetch x(1) into regs
        float4 pa = *(const float4*)(xp);
        float4 pb = *(const float4*)(xp + 4);
        write_x(pa, pb, 0);
        pa = *(const float4*)(xp + 64);
        pb = *(const float4*)(xp + 64 + 4);
        __syncthreads();                                // barrier #2
        for (int s = 0; s < T_STEPS + 2; ++s) {
            float4 na, nb;
            const bool ld = (s + 2 < T_STEPS);
            if (ld) {                                   // issue x(s+2) early
                na = *(const float4*)(xp + (size_t)(s + 2) * 64);
                nb = *(const float4*)(xp + (size_t)(s + 2) * 64 + 4);
            }
            if (s + 1 < T_STEPS) write_x(pa, pb, s + 1);   // waits on load from s-1
            if (ld) { pa = na; pb = nb; }
            BAR();
        }
    }

    __syncthreads();
    // =================== dense head ===================
    if (tid < BT) {
        float acc = bd[0];
#pragma unroll
        for (int j = 0; j < 16; ++j) acc += h2last[tid][j] * Wd[j];
        out[bbase + tid] = acc;
    }
}

extern "C" void kernel_launch(void* const* d_in, const int* in_sizes, int n_in,
                              void* d_out, int out_size, void* d_ws, size_t ws_size,
                              hipStream_t stream) {
    (void)in_sizes; (void)n_in; (void)d_ws; (void)ws_size; (void)out_size;
    const float* x  = (const float*)d_in[0];
    const float* W0 = (const float*)d_in[1];
    const float* U0 = (const float*)d_in[2];
    const float* b0 = (const float*)d_in[3];
    const float* W1 = (const float*)d_in[4];
    const float* U1 = (const float*)d_in[5];
    const float* b1 = (const float*)d_in[6];
    const float* W2 = (const float*)d_in[7];
    const float* U2 = (const float*)d_in[8];
    const float* b2 = (const float*)d_in[9];
    const float* Wd = (const float*)d_in[10];
    const float* bd = (const float*)d_in[11];
    float* out = (float*)d_out;

    dim3 grid(2048 / BT);   // 256 blocks, 1 per CU
    dim3 block(512);        // 8 waves, 2 per SIMD
    hipLaunchKernelGGL(lstm_pipe, grid, block, 0, stream,
                       x, W0, U0, b0, W1, U1, b1, W2, U2, b2, Wd, bd, out);
}